// Round 2
// baseline (2623.123 us; speedup 1.0000x reference)
//
#include <hip/hip_runtime.h>

// HyperDiffusion: coarse counting-sort binning (bucket = 32 segments) +
// per-bucket LDS-accumulated gather. No exact CSR scatter, no float global atomics.

#define C_DIM 128
#define W_BKT 32            // segments per bucket (both directions)
#define W_SHIFT 5
#define BIN_THREADS 256
#define BIN_ITEMS 16        // 4096 incidences per bin-pass block

__global__ __launch_bounds__(256) void zero_int_kernel(int* __restrict__ p, int n) {
    int i = blockIdx.x * blockDim.x + threadIdx.x;
    if (i < n) p[i] = 0;
}

__global__ __launch_bounds__(256) void hist_kernel(const int* __restrict__ v_ids,
                                                   const int* __restrict__ e_ids,
                                                   int* __restrict__ deg_v,
                                                   int* __restrict__ deg_e, int nnz) {
    int k = blockIdx.x * blockDim.x + threadIdx.x;
    if (k < nnz) {
        atomicAdd(&deg_v[v_ids[k]], 1);
        atomicAdd(&deg_e[e_ids[k]], 1);
    }
}

// Two independent single-block exclusive scans (block 0: edges, block 1: vertices),
// also emitting inv_deg.
__global__ __launch_bounds__(1024) void scan2_kernel(
    const int* __restrict__ deg_e, int* __restrict__ off_e, float* __restrict__ inv_e, int n_e,
    const int* __restrict__ deg_v, int* __restrict__ off_v, float* __restrict__ inv_v, int n_v) {
    const int* deg; int* off; float* inv; int n;
    if (blockIdx.x == 0) { deg = deg_e; off = off_e; inv = inv_e; n = n_e; }
    else                 { deg = deg_v; off = off_v; inv = inv_v; n = n_v; }

    __shared__ int wsum[16];
    __shared__ int s_carry;
    __shared__ int s_total;
    const int tid = threadIdx.x;
    const int lane = tid & 63;
    const int wid = tid >> 6;
    if (tid == 0) s_carry = 0;
    __syncthreads();
    for (int base = 0; base < n; base += 4096) {
        int idx = base + tid * 4;
        int v0 = 0, v1 = 0, v2 = 0, v3 = 0;
        if (idx + 3 < n) {
            v0 = deg[idx]; v1 = deg[idx + 1]; v2 = deg[idx + 2]; v3 = deg[idx + 3];
        } else {
            if (idx     < n) v0 = deg[idx];
            if (idx + 1 < n) v1 = deg[idx + 1];
            if (idx + 2 < n) v2 = deg[idx + 2];
            if (idx + 3 < n) v3 = deg[idx + 3];
        }
        int tsum = v0 + v1 + v2 + v3;
        int x = tsum;
        #pragma unroll
        for (int d = 1; d < 64; d <<= 1) {
            int y = __shfl_up(x, d, 64);
            if (lane >= d) x += y;
        }
        if (lane == 63) wsum[wid] = x;
        __syncthreads();
        if (tid == 0) {
            int run = 0;
            #pragma unroll
            for (int i = 0; i < 16; ++i) { int t = wsum[i]; wsum[i] = run; run += t; }
            s_total = run;
        }
        __syncthreads();
        int excl = s_carry + wsum[wid] + (x - tsum);
        if (idx < n)     { off[idx]     = excl;                inv[idx]     = v0 > 0 ? 1.0f / (float)v0 : 0.0f; }
        if (idx + 1 < n) { off[idx + 1] = excl + v0;           inv[idx + 1] = v1 > 0 ? 1.0f / (float)v1 : 0.0f; }
        if (idx + 2 < n) { off[idx + 2] = excl + v0 + v1;      inv[idx + 2] = v2 > 0 ? 1.0f / (float)v2 : 0.0f; }
        if (idx + 3 < n) { off[idx + 3] = excl + v0 + v1 + v2; inv[idx + 3] = v3 > 0 ? 1.0f / (float)v3 : 0.0f; }
        __syncthreads();
        if (tid == 0) s_carry += s_total;
        __syncthreads();
    }
    if (tid == 0) off[n] = s_carry;
}

// Coarse counting-sort: records (key_segment, source_id) grouped to bucket
// granularity (W_BKT segments). Bucket base in bins = off[bucket*W_BKT] (CSR
// offset), so bucket ranges are exactly [off[32b], off[32b+32]).
__global__ __launch_bounds__(BIN_THREADS) void bin_kernel(
    const int* __restrict__ v_ids, const int* __restrict__ e_ids,
    const int* __restrict__ off_v, const int* __restrict__ off_e,
    int* __restrict__ binCurE, int* __restrict__ binCurV,
    int2* __restrict__ binsE, int2* __restrict__ binsV,
    int nnz, int nbE, int nbV) {
    extern __shared__ int smem[];
    int* cntE = smem;            // nbE
    int* cntV = cntE + nbE;      // nbV
    int* gbE  = cntV + nbV;      // nbE
    int* gbV  = gbE + nbE;       // nbV

    for (int i = threadIdx.x; i < nbE + nbV; i += BIN_THREADS) cntE[i] = 0;
    __syncthreads();

    const int base = blockIdx.x * (BIN_THREADS * BIN_ITEMS);
    int v[BIN_ITEMS], e[BIN_ITEMS], rE[BIN_ITEMS], rV[BIN_ITEMS];
    #pragma unroll
    for (int k = 0; k < BIN_ITEMS; ++k) e[k] = -1;

    #pragma unroll
    for (int c = 0; c < BIN_ITEMS / 4; ++c) {
        int idx = base + (c * BIN_THREADS + threadIdx.x) * 4;
        if (idx + 3 < nnz) {
            int4 tv = *reinterpret_cast<const int4*>(v_ids + idx);
            int4 te = *reinterpret_cast<const int4*>(e_ids + idx);
            v[c*4+0] = tv.x; v[c*4+1] = tv.y; v[c*4+2] = tv.z; v[c*4+3] = tv.w;
            e[c*4+0] = te.x; e[c*4+1] = te.y; e[c*4+2] = te.z; e[c*4+3] = te.w;
        } else {
            #pragma unroll
            for (int u = 0; u < 4; ++u) {
                int id2 = idx + u;
                if (id2 < nnz) { v[c*4+u] = v_ids[id2]; e[c*4+u] = e_ids[id2]; }
            }
        }
    }

    // phase 1: count + capture local rank
    #pragma unroll
    for (int k = 0; k < BIN_ITEMS; ++k) {
        if (e[k] >= 0) {
            rE[k] = atomicAdd(&cntE[e[k] >> W_SHIFT], 1);
            rV[k] = atomicAdd(&cntV[v[k] >> W_SHIFT], 1);
        }
    }
    __syncthreads();
    // reserve contiguous runs per bucket
    for (int b = threadIdx.x; b < nbE; b += BIN_THREADS) {
        int c = cntE[b];
        if (c > 0) gbE[b] = off_e[b << W_SHIFT] + atomicAdd(&binCurE[b], c);
    }
    for (int b = threadIdx.x; b < nbV; b += BIN_THREADS) {
        int c = cntV[b];
        if (c > 0) gbV[b] = off_v[b << W_SHIFT] + atomicAdd(&binCurV[b], c);
    }
    __syncthreads();
    // phase 2: direct clustered writes
    #pragma unroll
    for (int k = 0; k < BIN_ITEMS; ++k) {
        if (e[k] >= 0) {
            binsE[gbE[e[k] >> W_SHIFT] + rE[k]] = make_int2(e[k], v[k]);
            binsV[gbV[v[k] >> W_SHIFT] + rV[k]] = make_int2(v[k], e[k]);
        }
    }
}

// Per-bucket gather: block owns W_BKT consecutive segments; records consumed
// wave-serially with 2-deep prefetch; accumulate into 16 KB LDS via ds_add_f32;
// dense float4 writeout. Weight is by SOURCE id for both directions.
__global__ __launch_bounds__(256) void gather_kernel(
    const float* __restrict__ rows,      // [n_src, 128]
    const float* __restrict__ inv_deg,   // per-source weight
    const int* __restrict__ off,         // CSR offsets of target segments
    const int2* __restrict__ bins,       // (target, source) grouped to buckets
    float* __restrict__ out, int n_seg) {
    __shared__ float acc[W_BKT * C_DIM]; // 16 KB
    const int b = blockIdx.x;
    const int sLo = b * W_BKT;
    const int sCnt = min(W_BKT, n_seg - sLo);
    const int r0 = off[sLo];
    const int r1 = off[sLo + sCnt];
    for (int i = threadIdx.x; i < W_BKT * C_DIM; i += 256) acc[i] = 0.0f;
    __syncthreads();

    const int wid = threadIdx.x >> 6, lane = threadIdx.x & 63;
    const int cnt = r1 - r0;
    const int per = (cnt + 3) >> 2;
    int j = r0 + wid * per;
    const int jend = min(r1, j + per);

    int2 rA, rB; float wA = 0.0f, wB = 0.0f;
    if (j < jend)     { rA = bins[j];     wA = inv_deg[rA.y]; }
    if (j + 1 < jend) { rB = bins[j + 1]; wB = inv_deg[rB.y]; }
    for (; j + 1 < jend; j += 2) {
        int2 rC, rD; float wC = 0.0f, wD = 0.0f;
        if (j + 2 < jend) { rC = bins[j + 2]; wC = inv_deg[rC.y]; }
        if (j + 3 < jend) { rD = bins[j + 3]; wD = inv_deg[rD.y]; }
        float2 xA = *reinterpret_cast<const float2*>(rows + (size_t)rA.y * C_DIM + lane * 2);
        float2 xB = *reinterpret_cast<const float2*>(rows + (size_t)rB.y * C_DIM + lane * 2);
        float* pA = &acc[(rA.x - sLo) * C_DIM + lane * 2];
        atomicAdd(pA,     xA.x * wA);
        atomicAdd(pA + 1, xA.y * wA);
        float* pB = &acc[(rB.x - sLo) * C_DIM + lane * 2];
        atomicAdd(pB,     xB.x * wB);
        atomicAdd(pB + 1, xB.y * wB);
        rA = rC; wA = wC; rB = rD; wB = wD;
    }
    if (j < jend) {
        float2 xA = *reinterpret_cast<const float2*>(rows + (size_t)rA.y * C_DIM + lane * 2);
        float* pA = &acc[(rA.x - sLo) * C_DIM + lane * 2];
        atomicAdd(pA,     xA.x * wA);
        atomicAdd(pA + 1, xA.y * wA);
    }
    __syncthreads();
    const int nfl = sCnt * C_DIM;
    for (int i = threadIdx.x * 4; i < nfl; i += 256 * 4) {
        *reinterpret_cast<float4*>(&out[(size_t)sLo * C_DIM + i]) =
            *reinterpret_cast<const float4*>(&acc[i]);
    }
}

extern "C" void kernel_launch(void* const* d_in, const int* in_sizes, int n_in,
                              void* d_out, int out_size, void* d_ws, size_t ws_size,
                              hipStream_t stream) {
    const float* X   = (const float*)d_in[0];
    const int* v_ids = (const int*)d_in[1];
    const int* e_ids = (const int*)d_in[2];

    const int n_v = in_sizes[0] / C_DIM;
    const int nnz = in_sizes[1];
    const int n_e = out_size / C_DIM - n_v;
    const int nbE = (n_e + W_BKT - 1) / W_BKT;
    const int nbV = (n_v + W_BKT - 1) / W_BKT;

    float* node_feat = (float*)d_out;                       // [n_v, 128]
    float* edge_feat = (float*)d_out + (size_t)n_v * C_DIM; // [n_e, 128]

    // workspace layout (4B units, zero-region first and contiguous)
    int* ws = (int*)d_ws;
    size_t cur = 0;
    int* deg_v   = ws + cur; cur += n_v;
    int* deg_e   = ws + cur; cur += n_e;
    int* binCurE = ws + cur; cur += nbE;
    int* binCurV = ws + cur; cur += nbV;
    int* off_e   = ws + cur; cur += n_e + 1;
    int* off_v   = ws + cur; cur += n_v + 1;
    float* inv_e = (float*)(ws + cur); cur += n_e;
    float* inv_v = (float*)(ws + cur); cur += n_v;
    cur = (cur + 1) & ~(size_t)1;  // 8B align
    int2* binsE = (int2*)(ws + cur); cur += 2 * (size_t)nnz;
    int2* binsV = (int2*)(ws + cur); cur += 2 * (size_t)nnz;

    // 1. zero degree histograms + bucket cursors
    {
        int nzero = n_v + n_e + nbE + nbV;
        zero_int_kernel<<<(nzero + 255) / 256, 256, 0, stream>>>(deg_v, nzero);
    }
    // 2. degree histograms
    hist_kernel<<<(nnz + 255) / 256, 256, 0, stream>>>(v_ids, e_ids, deg_v, deg_e, nnz);
    // 3. both exclusive scans concurrently (+ inverse degrees)
    scan2_kernel<<<2, 1024, 0, stream>>>(deg_e, off_e, inv_e, n_e, deg_v, off_v, inv_v, n_v);
    // 4. coarse counting-sort binning (both directions, one pass)
    {
        int nblk = (nnz + BIN_THREADS * BIN_ITEMS - 1) / (BIN_THREADS * BIN_ITEMS);
        size_t smem = (size_t)(2 * (nbE + nbV)) * sizeof(int);
        bin_kernel<<<nblk, BIN_THREADS, smem, stream>>>(v_ids, e_ids, off_v, off_e,
                                                        binCurE, binCurV, binsE, binsV,
                                                        nnz, nbE, nbV);
    }
    // 5. v2e: edge_feat[e] = sum X[v] * inv_deg_v[v]
    gather_kernel<<<nbE, 256, 0, stream>>>(X, inv_v, off_e, binsE, edge_feat, n_e);
    // 6. e2v: node_feat[v] = sum edge_feat[e] * inv_deg_e[e]
    gather_kernel<<<nbV, 256, 0, stream>>>(edge_feat, inv_e, off_v, binsV, node_feat, n_v);
}

// Round 3
// 584.196 us; speedup vs baseline: 4.4901x; 4.4901x over previous
//
#include <hip/hip_runtime.h>

// HyperDiffusion: hist -> scan -> coarse bin (packed, clustered writes) ->
// refine to exact CSR (LDS rank, window-local writes) ->
// wave-per-segment gathers with 4-deep ILP. No float atomics anywhere.

#define C_DIM 128
#define W_BKT 32            // segments per bucket
#define W_SHIFT 5
#define BIN_THREADS 256
#define BIN_ITEMS 16        // 4096 incidences per bin-pass block

__global__ __launch_bounds__(256) void zero_int_kernel(int* __restrict__ p, int n) {
    int i = blockIdx.x * blockDim.x + threadIdx.x;
    if (i < n) p[i] = 0;
}

__global__ __launch_bounds__(256) void hist_kernel(const int* __restrict__ v_ids,
                                                   const int* __restrict__ e_ids,
                                                   int* __restrict__ deg_v,
                                                   int* __restrict__ deg_e, int nnz) {
    int k = blockIdx.x * blockDim.x + threadIdx.x;
    if (k < nnz) {
        atomicAdd(&deg_v[v_ids[k]], 1);
        atomicAdd(&deg_e[e_ids[k]], 1);
    }
}

// Two independent single-block exclusive scans (block 0: edges, block 1: vertices),
// also emitting inv_deg = deg>0 ? 1/deg : 0.
__global__ __launch_bounds__(1024) void scan2_kernel(
    const int* __restrict__ deg_e, int* __restrict__ off_e, float* __restrict__ inv_e, int n_e,
    const int* __restrict__ deg_v, int* __restrict__ off_v, float* __restrict__ inv_v, int n_v) {
    const int* deg; int* off; float* inv; int n;
    if (blockIdx.x == 0) { deg = deg_e; off = off_e; inv = inv_e; n = n_e; }
    else                 { deg = deg_v; off = off_v; inv = inv_v; n = n_v; }

    __shared__ int wsum[16];
    __shared__ int s_carry;
    __shared__ int s_total;
    const int tid = threadIdx.x;
    const int lane = tid & 63;
    const int wid = tid >> 6;
    if (tid == 0) s_carry = 0;
    __syncthreads();
    for (int base = 0; base < n; base += 4096) {
        int idx = base + tid * 4;
        int v0 = 0, v1 = 0, v2 = 0, v3 = 0;
        if (idx + 3 < n) {
            v0 = deg[idx]; v1 = deg[idx + 1]; v2 = deg[idx + 2]; v3 = deg[idx + 3];
        } else {
            if (idx     < n) v0 = deg[idx];
            if (idx + 1 < n) v1 = deg[idx + 1];
            if (idx + 2 < n) v2 = deg[idx + 2];
            if (idx + 3 < n) v3 = deg[idx + 3];
        }
        int tsum = v0 + v1 + v2 + v3;
        int x = tsum;
        #pragma unroll
        for (int d = 1; d < 64; d <<= 1) {
            int y = __shfl_up(x, d, 64);
            if (lane >= d) x += y;
        }
        if (lane == 63) wsum[wid] = x;
        __syncthreads();
        if (tid == 0) {
            int run = 0;
            #pragma unroll
            for (int i = 0; i < 16; ++i) { int t = wsum[i]; wsum[i] = run; run += t; }
            s_total = run;
        }
        __syncthreads();
        int excl = s_carry + wsum[wid] + (x - tsum);
        if (idx < n)     { off[idx]     = excl;                inv[idx]     = v0 > 0 ? 1.0f / (float)v0 : 0.0f; }
        if (idx + 1 < n) { off[idx + 1] = excl + v0;           inv[idx + 1] = v1 > 0 ? 1.0f / (float)v1 : 0.0f; }
        if (idx + 2 < n) { off[idx + 2] = excl + v0 + v1;      inv[idx + 2] = v2 > 0 ? 1.0f / (float)v2 : 0.0f; }
        if (idx + 3 < n) { off[idx + 3] = excl + v0 + v1 + v2; inv[idx + 3] = v3 > 0 ? 1.0f / (float)v3 : 0.0f; }
        __syncthreads();
        if (tid == 0) s_carry += s_total;
        __syncthreads();
    }
    if (tid == 0) off[n] = s_carry;
}

// Coarse counting-sort into buckets of W_BKT segments. Record is PACKED:
// (seg & 31) << 20 | source_id  (source < 2^20). Bucket base = off[bucket*32],
// so each bucket's records occupy exactly [off[32b], off[32b+32]).
__global__ __launch_bounds__(BIN_THREADS) void bin_kernel(
    const int* __restrict__ v_ids, const int* __restrict__ e_ids,
    const int* __restrict__ off_v, const int* __restrict__ off_e,
    int* __restrict__ binCurE, int* __restrict__ binCurV,
    int* __restrict__ binsE, int* __restrict__ binsV,
    int nnz, int nbE, int nbV) {
    extern __shared__ int smem[];
    int* cntE = smem;            // nbE
    int* cntV = cntE + nbE;      // nbV
    int* gbE  = cntV + nbV;      // nbE
    int* gbV  = gbE + nbE;       // nbV

    for (int i = threadIdx.x; i < nbE + nbV; i += BIN_THREADS) cntE[i] = 0;
    __syncthreads();

    const int base = blockIdx.x * (BIN_THREADS * BIN_ITEMS);
    int v[BIN_ITEMS], e[BIN_ITEMS], rE[BIN_ITEMS], rV[BIN_ITEMS];
    #pragma unroll
    for (int k = 0; k < BIN_ITEMS; ++k) e[k] = -1;

    #pragma unroll
    for (int c = 0; c < BIN_ITEMS / 4; ++c) {
        int idx = base + (c * BIN_THREADS + threadIdx.x) * 4;
        if (idx + 3 < nnz) {
            int4 tv = *reinterpret_cast<const int4*>(v_ids + idx);
            int4 te = *reinterpret_cast<const int4*>(e_ids + idx);
            v[c*4+0] = tv.x; v[c*4+1] = tv.y; v[c*4+2] = tv.z; v[c*4+3] = tv.w;
            e[c*4+0] = te.x; e[c*4+1] = te.y; e[c*4+2] = te.z; e[c*4+3] = te.w;
        } else {
            #pragma unroll
            for (int u = 0; u < 4; ++u) {
                int id2 = idx + u;
                if (id2 < nnz) { v[c*4+u] = v_ids[id2]; e[c*4+u] = e_ids[id2]; }
            }
        }
    }

    // phase 1: per-block bucket histograms + local ranks
    #pragma unroll
    for (int k = 0; k < BIN_ITEMS; ++k) {
        if (e[k] >= 0) {
            rE[k] = atomicAdd(&cntE[e[k] >> W_SHIFT], 1);
            rV[k] = atomicAdd(&cntV[v[k] >> W_SHIFT], 1);
        }
    }
    __syncthreads();
    // reserve contiguous runs per bucket
    for (int b = threadIdx.x; b < nbE; b += BIN_THREADS) {
        int c = cntE[b];
        if (c > 0) gbE[b] = off_e[b << W_SHIFT] + atomicAdd(&binCurE[b], c);
    }
    for (int b = threadIdx.x; b < nbV; b += BIN_THREADS) {
        int c = cntV[b];
        if (c > 0) gbV[b] = off_v[b << W_SHIFT] + atomicAdd(&binCurV[b], c);
    }
    __syncthreads();
    // phase 2: clustered packed writes
    #pragma unroll
    for (int k = 0; k < BIN_ITEMS; ++k) {
        if (e[k] >= 0) {
            binsE[gbE[e[k] >> W_SHIFT] + rE[k]] = ((e[k] & (W_BKT - 1)) << 20) | v[k];
            binsV[gbV[v[k] >> W_SHIFT] + rV[k]] = ((v[k] & (W_BKT - 1)) << 20) | e[k];
        }
    }
}

// Refine: one block per bucket; exact per-segment rank via 32 LDS counters.
// Writes land randomly but only within the bucket's contiguous (fully dirtied)
// window -> no write amplification. First nbE blocks: edge dir; rest: vertex dir.
__global__ __launch_bounds__(256) void refine_kernel(
    const int* __restrict__ binsE, const int* __restrict__ off_e, int* __restrict__ adj_e, int n_e, int nbE,
    const int* __restrict__ binsV, const int* __restrict__ off_v, int* __restrict__ adj_v, int n_v) {
    const int* bins; const int* off; int* adj; int nseg; int b;
    if ((int)blockIdx.x < nbE) { bins = binsE; off = off_e; adj = adj_e; nseg = n_e; b = blockIdx.x; }
    else                       { bins = binsV; off = off_v; adj = adj_v; nseg = n_v; b = blockIdx.x - nbE; }

    __shared__ int cnt[W_BKT];
    if (threadIdx.x < W_BKT) cnt[threadIdx.x] = 0;
    __syncthreads();

    const int sLo = b << W_SHIFT;
    const int sCnt = min(W_BKT, nseg - sLo);
    const int r0 = off[sLo];
    const int r1 = off[sLo + sCnt];
    for (int j = r0 + threadIdx.x; j < r1; j += 256) {
        int rec = bins[j];
        int local = rec >> 20;
        int src = rec & 0xFFFFF;
        int rank = atomicAdd(&cnt[local], 1);
        adj[off[sLo + local] + rank] = src;
    }
}

// Gather: one wave per segment, lane = 2 channels. 4-deep unroll with 4
// independent accumulators -> 4 row loads + 4 weight loads in flight.
// out[s] = sum_j w[adj[j]] * rows[adj[j]]
__global__ __launch_bounds__(256) void gather_kernel(
    const float* __restrict__ rows, const float* __restrict__ w,
    const int* __restrict__ off, const int* __restrict__ adj,
    float* __restrict__ out, int n_seg) {
    const int seg = blockIdx.x * 4 + (threadIdx.x >> 6);
    if (seg >= n_seg) return;
    const int lane = threadIdx.x & 63;
    int j = off[seg];
    const int end = off[seg + 1];

    float2 a0 = make_float2(0.f, 0.f), a1 = a0, a2 = a0, a3 = a0;
    for (; j + 3 < end; j += 4) {
        int s0 = adj[j], s1 = adj[j + 1], s2 = adj[j + 2], s3 = adj[j + 3];
        float w0 = w[s0], w1 = w[s1], w2 = w[s2], w3 = w[s3];
        float2 x0 = *reinterpret_cast<const float2*>(rows + (size_t)s0 * C_DIM + lane * 2);
        float2 x1 = *reinterpret_cast<const float2*>(rows + (size_t)s1 * C_DIM + lane * 2);
        float2 x2 = *reinterpret_cast<const float2*>(rows + (size_t)s2 * C_DIM + lane * 2);
        float2 x3 = *reinterpret_cast<const float2*>(rows + (size_t)s3 * C_DIM + lane * 2);
        a0.x += x0.x * w0; a0.y += x0.y * w0;
        a1.x += x1.x * w1; a1.y += x1.y * w1;
        a2.x += x2.x * w2; a2.y += x2.y * w2;
        a3.x += x3.x * w3; a3.y += x3.y * w3;
    }
    for (; j < end; ++j) {
        int s0 = adj[j];
        float w0 = w[s0];
        float2 x0 = *reinterpret_cast<const float2*>(rows + (size_t)s0 * C_DIM + lane * 2);
        a0.x += x0.x * w0; a0.y += x0.y * w0;
    }
    float2 r;
    r.x = (a0.x + a1.x) + (a2.x + a3.x);
    r.y = (a0.y + a1.y) + (a2.y + a3.y);
    *reinterpret_cast<float2*>(out + (size_t)seg * C_DIM + lane * 2) = r;
}

extern "C" void kernel_launch(void* const* d_in, const int* in_sizes, int n_in,
                              void* d_out, int out_size, void* d_ws, size_t ws_size,
                              hipStream_t stream) {
    const float* X   = (const float*)d_in[0];
    const int* v_ids = (const int*)d_in[1];
    const int* e_ids = (const int*)d_in[2];

    const int n_v = in_sizes[0] / C_DIM;
    const int nnz = in_sizes[1];
    const int n_e = out_size / C_DIM - n_v;
    const int nbE = (n_e + W_BKT - 1) / W_BKT;
    const int nbV = (n_v + W_BKT - 1) / W_BKT;

    float* node_feat = (float*)d_out;                       // [n_v, 128]
    float* edge_feat = (float*)d_out + (size_t)n_v * C_DIM; // [n_e, 128]

    // workspace layout (4B units; zero-region first and contiguous)
    int* ws = (int*)d_ws;
    size_t cur = 0;
    int* deg_v   = ws + cur; cur += n_v;
    int* deg_e   = ws + cur; cur += n_e;
    int* binCurE = ws + cur; cur += nbE;
    int* binCurV = ws + cur; cur += nbV;
    int* off_e   = ws + cur; cur += n_e + 1;
    int* off_v   = ws + cur; cur += n_v + 1;
    float* inv_e = (float*)(ws + cur); cur += n_e;
    float* inv_v = (float*)(ws + cur); cur += n_v;
    int* binsE = ws + cur; cur += nnz;
    int* binsV = ws + cur; cur += nnz;
    int* adj_e = ws + cur; cur += nnz;
    int* adj_v = ws + cur; cur += nnz;

    // 1. zero degree histograms + bucket cursors (contiguous)
    {
        int nzero = n_v + n_e + nbE + nbV;
        zero_int_kernel<<<(nzero + 255) / 256, 256, 0, stream>>>(deg_v, nzero);
    }
    // 2. degree histograms
    hist_kernel<<<(nnz + 255) / 256, 256, 0, stream>>>(v_ids, e_ids, deg_v, deg_e, nnz);
    // 3. both exclusive scans concurrently (+ inverse degrees)
    scan2_kernel<<<2, 1024, 0, stream>>>(deg_e, off_e, inv_e, n_e, deg_v, off_v, inv_v, n_v);
    // 4. coarse counting-sort binning (both directions, packed records)
    {
        int nblk = (nnz + BIN_THREADS * BIN_ITEMS - 1) / (BIN_THREADS * BIN_ITEMS);
        size_t smem = (size_t)(2 * (nbE + nbV)) * sizeof(int);
        bin_kernel<<<nblk, BIN_THREADS, smem, stream>>>(v_ids, e_ids, off_v, off_e,
                                                        binCurE, binCurV, binsE, binsV,
                                                        nnz, nbE, nbV);
    }
    // 5. refine to exact CSR (both directions in one launch)
    refine_kernel<<<nbE + nbV, 256, 0, stream>>>(binsE, off_e, adj_e, n_e, nbE,
                                                 binsV, off_v, adj_v, n_v);
    // 6. v2e: edge_feat[e] = sum_v X[v] * inv_deg_v[v]
    gather_kernel<<<(n_e + 3) / 4, 256, 0, stream>>>(X, inv_v, off_e, adj_e, edge_feat, n_e);
    // 7. e2v: node_feat[v] = sum_e edge_feat[e] * inv_deg_e[e]
    gather_kernel<<<(n_v + 3) / 4, 256, 0, stream>>>(edge_feat, inv_e, off_v, adj_v, node_feat, n_v);
}

// Round 4
// 392.844 us; speedup vs baseline: 6.6773x; 1.4871x over previous
//
#include <hip/hip_runtime.h>

// HyperDiffusion, atomic-free pipeline:
//   count (per-block LDS bucket hist -> counts[NB][NBLK], non-atomic)
//   colscan (wave per bucket: exclusive scan over the NBLK blocks + totals)
//   bscan  (single-block exclusive scan over NB bucket totals -> bucketOff)
//   place  (re-read ids, LDS rank + base -> packed records, clustered writes)
//   refine (per bucket: per-segment counts -> off/inv/adj, window-local writes)
//   gather x2 (wave per segment, 4-deep ILP, float2 lanes)
//
// Bucket = 64 consecutive segments. E-buckets [0,nbE), V-buckets [nbE,NB).
// Record = (seg&63)<<20 | src  (src < 2^20). bins/adj are combined 2*nnz arrays:
// E region [0,nnz), V region [nnz,2*nnz). All offsets absolute into those arrays.

#define C_DIM 128
#define W_BKT 64
#define W_SHIFT 6
#define NBLK 128            // partition blocks for count/place (must match!)

// ---------- 1. count: per-block bucket histogram, non-atomic flush ----------
__global__ __launch_bounds__(256) void count_kernel(
    const int* __restrict__ v_ids, const int* __restrict__ e_ids,
    int* __restrict__ counts, int nnz, int nbE, int nb, int itemsPerBlk) {
    extern __shared__ int hist[];  // nb
    for (int i = threadIdx.x; i < nb; i += 256) hist[i] = 0;
    __syncthreads();
    const int beg = blockIdx.x * itemsPerBlk;
    const int end = min(nnz, beg + itemsPerBlk);
    for (int idx = beg + threadIdx.x * 4; idx < end; idx += 256 * 4) {
        if (idx + 3 < end) {
            int4 tv = *reinterpret_cast<const int4*>(v_ids + idx);
            int4 te = *reinterpret_cast<const int4*>(e_ids + idx);
            atomicAdd(&hist[te.x >> W_SHIFT], 1);
            atomicAdd(&hist[te.y >> W_SHIFT], 1);
            atomicAdd(&hist[te.z >> W_SHIFT], 1);
            atomicAdd(&hist[te.w >> W_SHIFT], 1);
            atomicAdd(&hist[nbE + (tv.x >> W_SHIFT)], 1);
            atomicAdd(&hist[nbE + (tv.y >> W_SHIFT)], 1);
            atomicAdd(&hist[nbE + (tv.z >> W_SHIFT)], 1);
            atomicAdd(&hist[nbE + (tv.w >> W_SHIFT)], 1);
        } else {
            for (int u = 0; u < 4 && idx + u < end; ++u) {
                atomicAdd(&hist[e_ids[idx + u] >> W_SHIFT], 1);
                atomicAdd(&hist[nbE + (v_ids[idx + u] >> W_SHIFT)], 1);
            }
        }
    }
    __syncthreads();
    for (int i = threadIdx.x; i < nb; i += 256)
        counts[i * NBLK + blockIdx.x] = hist[i];
}

// ---------- 2. colscan: wave per bucket, exclusive scan over NBLK blocks ----------
__global__ __launch_bounds__(256) void colscan_kernel(
    int* __restrict__ counts, int* __restrict__ totals, int nb) {
    const int b = blockIdx.x * 4 + (threadIdx.x >> 6);
    if (b >= nb) return;
    const int lane = threadIdx.x & 63;
    int2 c = *reinterpret_cast<int2*>(counts + (size_t)b * NBLK + lane * 2);
    int s = c.x + c.y;
    int x = s;
    #pragma unroll
    for (int d = 1; d < 64; d <<= 1) {
        int y = __shfl_up(x, d, 64);
        if (lane >= d) x += y;
    }
    int excl = x - s;
    *reinterpret_cast<int2*>(counts + (size_t)b * NBLK + lane * 2) = make_int2(excl, excl + c.x);
    if (lane == 63) totals[b] = x;
}

// ---------- 3. bscan: single-block exclusive scan of bucket totals ----------
__global__ __launch_bounds__(1024) void bscan_kernel(
    const int* __restrict__ totals, int* __restrict__ boff, int n) {
    __shared__ int wsum[16];
    __shared__ int s_carry, s_total;
    const int tid = threadIdx.x;
    const int lane = tid & 63;
    const int wid = tid >> 6;
    if (tid == 0) s_carry = 0;
    __syncthreads();
    for (int base = 0; base < n; base += 4096) {
        int idx = base + tid * 4;
        int v0 = idx     < n ? totals[idx]     : 0;
        int v1 = idx + 1 < n ? totals[idx + 1] : 0;
        int v2 = idx + 2 < n ? totals[idx + 2] : 0;
        int v3 = idx + 3 < n ? totals[idx + 3] : 0;
        int tsum = v0 + v1 + v2 + v3;
        int x = tsum;
        #pragma unroll
        for (int d = 1; d < 64; d <<= 1) {
            int y = __shfl_up(x, d, 64);
            if (lane >= d) x += y;
        }
        if (lane == 63) wsum[wid] = x;
        __syncthreads();
        if (tid == 0) {
            int run = 0;
            #pragma unroll
            for (int i = 0; i < 16; ++i) { int t = wsum[i]; wsum[i] = run; run += t; }
            s_total = run;
        }
        __syncthreads();
        int excl = s_carry + wsum[wid] + (x - tsum);
        if (idx     < n) boff[idx]     = excl;
        if (idx + 1 < n) boff[idx + 1] = excl + v0;
        if (idx + 2 < n) boff[idx + 2] = excl + v0 + v1;
        if (idx + 3 < n) boff[idx + 3] = excl + v0 + v1 + v2;
        __syncthreads();
        if (tid == 0) s_carry += s_total;
        __syncthreads();
    }
    if (tid == 0) boff[n] = s_carry;
}

// ---------- 4. place: packed records at base[blk][bucket]+rank ----------
__global__ __launch_bounds__(256) void place_kernel(
    const int* __restrict__ v_ids, const int* __restrict__ e_ids,
    const int* __restrict__ counts, const int* __restrict__ boff,
    int* __restrict__ bins, int nnz, int nbE, int nb, int itemsPerBlk) {
    extern __shared__ int smem[];
    int* base = smem;        // nb
    int* rank = smem + nb;   // nb
    for (int i = threadIdx.x; i < nb; i += 256) {
        base[i] = boff[i] + counts[(size_t)i * NBLK + blockIdx.x];
        rank[i] = 0;
    }
    __syncthreads();
    const int beg = blockIdx.x * itemsPerBlk;
    const int end = min(nnz, beg + itemsPerBlk);
    for (int idx = beg + threadIdx.x * 4; idx < end; idx += 256 * 4) {
        if (idx + 3 < end) {
            int4 tv = *reinterpret_cast<const int4*>(v_ids + idx);
            int4 te = *reinterpret_cast<const int4*>(e_ids + idx);
            #pragma unroll
            for (int u = 0; u < 4; ++u) {
                int e = u == 0 ? te.x : u == 1 ? te.y : u == 2 ? te.z : te.w;
                int v = u == 0 ? tv.x : u == 1 ? tv.y : u == 2 ? tv.z : tv.w;
                int be = e >> W_SHIFT;
                int bv = nbE + (v >> W_SHIFT);
                int re = atomicAdd(&rank[be], 1);
                bins[base[be] + re] = ((e & (W_BKT - 1)) << 20) | v;
                int rv = atomicAdd(&rank[bv], 1);
                bins[base[bv] + rv] = ((v & (W_BKT - 1)) << 20) | e;
            }
        } else {
            for (int u = 0; u < 4 && idx + u < end; ++u) {
                int e = e_ids[idx + u];
                int v = v_ids[idx + u];
                int be = e >> W_SHIFT;
                int bv = nbE + (v >> W_SHIFT);
                int re = atomicAdd(&rank[be], 1);
                bins[base[be] + re] = ((e & (W_BKT - 1)) << 20) | v;
                int rv = atomicAdd(&rank[bv], 1);
                bins[base[bv] + rv] = ((v & (W_BKT - 1)) << 20) | e;
            }
        }
    }
}

// ---------- 5. refine: exact CSR + inv_deg per segment, all bucket-local ----------
__global__ __launch_bounds__(256) void refine_kernel(
    const int* __restrict__ bins, const int* __restrict__ boff,
    int* __restrict__ adj,
    int* __restrict__ off_e, float* __restrict__ inv_e, int n_e,
    int* __restrict__ off_v, float* __restrict__ inv_v, int n_v,
    int nbE, int nb) {
    const int b = blockIdx.x;
    const bool isE = b < nbE;
    const int sLo = (isE ? b : b - nbE) << W_SHIFT;
    const int nseg = isE ? n_e : n_v;
    int* off = isE ? off_e : off_v;
    float* inv = isE ? inv_e : inv_v;

    __shared__ int cnt[W_BKT], cnt2[W_BKT], lofs[W_BKT];
    if (threadIdx.x < W_BKT) { cnt[threadIdx.x] = 0; cnt2[threadIdx.x] = 0; }
    __syncthreads();

    const int r0 = boff[b], r1 = boff[b + 1];
    for (int j = r0 + threadIdx.x; j < r1; j += 256)
        atomicAdd(&cnt[bins[j] >> 20], 1);
    __syncthreads();

    if (threadIdx.x < 64) {  // wave 0: scan the 64 counters
        int c = cnt[threadIdx.x];
        int x = c;
        #pragma unroll
        for (int d = 1; d < 64; d <<= 1) {
            int y = __shfl_up(x, d, 64);
            if ((threadIdx.x & 63) >= d) x += y;
        }
        int excl = x - c;
        lofs[threadIdx.x] = r0 + excl;
        int s = sLo + threadIdx.x;
        if (s < nseg) {
            off[s] = r0 + excl;
            inv[s] = c > 0 ? 1.0f / (float)c : 0.0f;
        }
    }
    __syncthreads();
    for (int j = r0 + threadIdx.x; j < r1; j += 256) {
        int rec = bins[j];
        int local = rec >> 20;
        int src = rec & 0xFFFFF;
        int r = atomicAdd(&cnt2[local], 1);
        adj[lofs[local] + r] = src;
    }
    if (threadIdx.x == 0) {
        if (b == nbE - 1) off_e[n_e] = boff[nbE];
        if (b == nb - 1)  off_v[n_v] = boff[nb];
    }
}

// ---------- 6/7. gather: wave per segment, 4-deep ILP ----------
__global__ __launch_bounds__(256) void gather_kernel(
    const float* __restrict__ rows, const float* __restrict__ w,
    const int* __restrict__ off, const int* __restrict__ adj,
    float* __restrict__ out, int n_seg) {
    const int seg = blockIdx.x * 4 + (threadIdx.x >> 6);
    if (seg >= n_seg) return;
    const int lane = threadIdx.x & 63;
    int j = off[seg];
    const int end = off[seg + 1];

    float2 a0 = make_float2(0.f, 0.f), a1 = a0, a2 = a0, a3 = a0;
    for (; j + 3 < end; j += 4) {
        int s0 = adj[j], s1 = adj[j + 1], s2 = adj[j + 2], s3 = adj[j + 3];
        float w0 = w[s0], w1 = w[s1], w2 = w[s2], w3 = w[s3];
        float2 x0 = *reinterpret_cast<const float2*>(rows + (size_t)s0 * C_DIM + lane * 2);
        float2 x1 = *reinterpret_cast<const float2*>(rows + (size_t)s1 * C_DIM + lane * 2);
        float2 x2 = *reinterpret_cast<const float2*>(rows + (size_t)s2 * C_DIM + lane * 2);
        float2 x3 = *reinterpret_cast<const float2*>(rows + (size_t)s3 * C_DIM + lane * 2);
        a0.x += x0.x * w0; a0.y += x0.y * w0;
        a1.x += x1.x * w1; a1.y += x1.y * w1;
        a2.x += x2.x * w2; a2.y += x2.y * w2;
        a3.x += x3.x * w3; a3.y += x3.y * w3;
    }
    for (; j < end; ++j) {
        int s0 = adj[j];
        float w0 = w[s0];
        float2 x0 = *reinterpret_cast<const float2*>(rows + (size_t)s0 * C_DIM + lane * 2);
        a0.x += x0.x * w0; a0.y += x0.y * w0;
    }
    float2 r;
    r.x = (a0.x + a1.x) + (a2.x + a3.x);
    r.y = (a0.y + a1.y) + (a2.y + a3.y);
    *reinterpret_cast<float2*>(out + (size_t)seg * C_DIM + lane * 2) = r;
}

extern "C" void kernel_launch(void* const* d_in, const int* in_sizes, int n_in,
                              void* d_out, int out_size, void* d_ws, size_t ws_size,
                              hipStream_t stream) {
    const float* X   = (const float*)d_in[0];
    const int* v_ids = (const int*)d_in[1];
    const int* e_ids = (const int*)d_in[2];

    const int n_v = in_sizes[0] / C_DIM;
    const int nnz = in_sizes[1];
    const int n_e = out_size / C_DIM - n_v;
    const int nbE = (n_e + W_BKT - 1) / W_BKT;
    const int nbV = (n_v + W_BKT - 1) / W_BKT;
    const int nb  = nbE + nbV;
    const int itemsPerBlk = (((nnz + NBLK - 1) / NBLK) + 3) & ~3;

    float* node_feat = (float*)d_out;                       // [n_v, 128]
    float* edge_feat = (float*)d_out + (size_t)n_v * C_DIM; // [n_e, 128]

    // workspace (4B units)
    int* ws = (int*)d_ws;
    size_t cur = 0;
    int* counts = ws + cur; cur += (size_t)nb * NBLK;
    int* totals = ws + cur; cur += nb;
    int* boff   = ws + cur; cur += nb + 1;
    int* off_e  = ws + cur; cur += n_e + 1;
    int* off_v  = ws + cur; cur += n_v + 1;
    float* inv_e = (float*)(ws + cur); cur += n_e;
    float* inv_v = (float*)(ws + cur); cur += n_v;
    int* bins = ws + cur; cur += 2 * (size_t)nnz;
    int* adj  = ws + cur; cur += 2 * (size_t)nnz;

    const size_t smem1 = (size_t)nb * sizeof(int);
    const size_t smem2 = 2 * (size_t)nb * sizeof(int);

    count_kernel<<<NBLK, 256, smem1, stream>>>(v_ids, e_ids, counts, nnz, nbE, nb, itemsPerBlk);
    colscan_kernel<<<(nb + 3) / 4, 256, 0, stream>>>(counts, totals, nb);
    bscan_kernel<<<1, 1024, 0, stream>>>(totals, boff, nb);
    place_kernel<<<NBLK, 256, smem2, stream>>>(v_ids, e_ids, counts, boff, bins,
                                               nnz, nbE, nb, itemsPerBlk);
    refine_kernel<<<nb, 256, 0, stream>>>(bins, boff, adj,
                                          off_e, inv_e, n_e,
                                          off_v, inv_v, n_v, nbE, nb);
    // v2e: edge_feat[e] = sum_v X[v] * inv_deg_v[v]
    gather_kernel<<<(n_e + 3) / 4, 256, 0, stream>>>(X, inv_v, off_e, adj, edge_feat, n_e);
    // e2v: node_feat[v] = sum_e edge_feat[e] * inv_deg_e[e]
    gather_kernel<<<(n_v + 3) / 4, 256, 0, stream>>>(edge_feat, inv_e, off_v, adj, node_feat, n_v);
}

// Round 5
// 386.472 us; speedup vs baseline: 6.7874x; 1.0165x over previous
//
#include <hip/hip_runtime.h>

// HyperDiffusion, atomic-free pipeline:
//   count (per-block LDS bucket hist -> counts[NB][NBLK], non-atomic)
//   colscan (wave per bucket: exclusive scan over the NBLK blocks + totals)
//   bscan  (single-block exclusive scan over NB bucket totals -> bucketOff)
//   place  (re-read ids, LDS rank + base -> packed records, clustered writes)
//   refine (per bucket: per-segment counts -> off/inv/adj, window-local writes)
//   gather x2 (wave per segment; float4 lanes, 2 rows per wave-load, 8-row ILP)

#define C_DIM 128
#define W_BKT 64
#define W_SHIFT 6
#define NBLK 128            // partition blocks for count/place (must match!)

// ---------- 1. count: per-block bucket histogram, non-atomic flush ----------
__global__ __launch_bounds__(256) void count_kernel(
    const int* __restrict__ v_ids, const int* __restrict__ e_ids,
    int* __restrict__ counts, int nnz, int nbE, int nb, int itemsPerBlk) {
    extern __shared__ int hist[];  // nb
    for (int i = threadIdx.x; i < nb; i += 256) hist[i] = 0;
    __syncthreads();
    const int beg = blockIdx.x * itemsPerBlk;
    const int end = min(nnz, beg + itemsPerBlk);
    for (int idx = beg + threadIdx.x * 4; idx < end; idx += 256 * 4) {
        if (idx + 3 < end) {
            int4 tv = *reinterpret_cast<const int4*>(v_ids + idx);
            int4 te = *reinterpret_cast<const int4*>(e_ids + idx);
            atomicAdd(&hist[te.x >> W_SHIFT], 1);
            atomicAdd(&hist[te.y >> W_SHIFT], 1);
            atomicAdd(&hist[te.z >> W_SHIFT], 1);
            atomicAdd(&hist[te.w >> W_SHIFT], 1);
            atomicAdd(&hist[nbE + (tv.x >> W_SHIFT)], 1);
            atomicAdd(&hist[nbE + (tv.y >> W_SHIFT)], 1);
            atomicAdd(&hist[nbE + (tv.z >> W_SHIFT)], 1);
            atomicAdd(&hist[nbE + (tv.w >> W_SHIFT)], 1);
        } else {
            for (int u = 0; u < 4 && idx + u < end; ++u) {
                atomicAdd(&hist[e_ids[idx + u] >> W_SHIFT], 1);
                atomicAdd(&hist[nbE + (v_ids[idx + u] >> W_SHIFT)], 1);
            }
        }
    }
    __syncthreads();
    for (int i = threadIdx.x; i < nb; i += 256)
        counts[i * NBLK + blockIdx.x] = hist[i];
}

// ---------- 2. colscan: wave per bucket, exclusive scan over NBLK blocks ----------
__global__ __launch_bounds__(256) void colscan_kernel(
    int* __restrict__ counts, int* __restrict__ totals, int nb) {
    const int b = blockIdx.x * 4 + (threadIdx.x >> 6);
    if (b >= nb) return;
    const int lane = threadIdx.x & 63;
    int2 c = *reinterpret_cast<int2*>(counts + (size_t)b * NBLK + lane * 2);
    int s = c.x + c.y;
    int x = s;
    #pragma unroll
    for (int d = 1; d < 64; d <<= 1) {
        int y = __shfl_up(x, d, 64);
        if (lane >= d) x += y;
    }
    int excl = x - s;
    *reinterpret_cast<int2*>(counts + (size_t)b * NBLK + lane * 2) = make_int2(excl, excl + c.x);
    if (lane == 63) totals[b] = x;
}

// ---------- 3. bscan: single-block exclusive scan of bucket totals ----------
__global__ __launch_bounds__(1024) void bscan_kernel(
    const int* __restrict__ totals, int* __restrict__ boff, int n) {
    __shared__ int wsum[16];
    __shared__ int s_carry, s_total;
    const int tid = threadIdx.x;
    const int lane = tid & 63;
    const int wid = tid >> 6;
    if (tid == 0) s_carry = 0;
    __syncthreads();
    for (int base = 0; base < n; base += 4096) {
        int idx = base + tid * 4;
        int v0 = idx     < n ? totals[idx]     : 0;
        int v1 = idx + 1 < n ? totals[idx + 1] : 0;
        int v2 = idx + 2 < n ? totals[idx + 2] : 0;
        int v3 = idx + 3 < n ? totals[idx + 3] : 0;
        int tsum = v0 + v1 + v2 + v3;
        int x = tsum;
        #pragma unroll
        for (int d = 1; d < 64; d <<= 1) {
            int y = __shfl_up(x, d, 64);
            if (lane >= d) x += y;
        }
        if (lane == 63) wsum[wid] = x;
        __syncthreads();
        if (tid == 0) {
            int run = 0;
            #pragma unroll
            for (int i = 0; i < 16; ++i) { int t = wsum[i]; wsum[i] = run; run += t; }
            s_total = run;
        }
        __syncthreads();
        int excl = s_carry + wsum[wid] + (x - tsum);
        if (idx     < n) boff[idx]     = excl;
        if (idx + 1 < n) boff[idx + 1] = excl + v0;
        if (idx + 2 < n) boff[idx + 2] = excl + v0 + v1;
        if (idx + 3 < n) boff[idx + 3] = excl + v0 + v1 + v2;
        __syncthreads();
        if (tid == 0) s_carry += s_total;
        __syncthreads();
    }
    if (tid == 0) boff[n] = s_carry;
}

// ---------- 4. place: packed records at base[blk][bucket]+rank ----------
__global__ __launch_bounds__(256) void place_kernel(
    const int* __restrict__ v_ids, const int* __restrict__ e_ids,
    const int* __restrict__ counts, const int* __restrict__ boff,
    int* __restrict__ bins, int nnz, int nbE, int nb, int itemsPerBlk) {
    extern __shared__ int smem[];
    int* base = smem;        // nb
    int* rank = smem + nb;   // nb
    for (int i = threadIdx.x; i < nb; i += 256) {
        base[i] = boff[i] + counts[(size_t)i * NBLK + blockIdx.x];
        rank[i] = 0;
    }
    __syncthreads();
    const int beg = blockIdx.x * itemsPerBlk;
    const int end = min(nnz, beg + itemsPerBlk);
    for (int idx = beg + threadIdx.x * 4; idx < end; idx += 256 * 4) {
        if (idx + 3 < end) {
            int4 tv = *reinterpret_cast<const int4*>(v_ids + idx);
            int4 te = *reinterpret_cast<const int4*>(e_ids + idx);
            #pragma unroll
            for (int u = 0; u < 4; ++u) {
                int e = u == 0 ? te.x : u == 1 ? te.y : u == 2 ? te.z : te.w;
                int v = u == 0 ? tv.x : u == 1 ? tv.y : u == 2 ? tv.z : tv.w;
                int be = e >> W_SHIFT;
                int bv = nbE + (v >> W_SHIFT);
                int re = atomicAdd(&rank[be], 1);
                bins[base[be] + re] = ((e & (W_BKT - 1)) << 20) | v;
                int rv = atomicAdd(&rank[bv], 1);
                bins[base[bv] + rv] = ((v & (W_BKT - 1)) << 20) | e;
            }
        } else {
            for (int u = 0; u < 4 && idx + u < end; ++u) {
                int e = e_ids[idx + u];
                int v = v_ids[idx + u];
                int be = e >> W_SHIFT;
                int bv = nbE + (v >> W_SHIFT);
                int re = atomicAdd(&rank[be], 1);
                bins[base[be] + re] = ((e & (W_BKT - 1)) << 20) | v;
                int rv = atomicAdd(&rank[bv], 1);
                bins[base[bv] + rv] = ((v & (W_BKT - 1)) << 20) | e;
            }
        }
    }
}

// ---------- 5. refine: exact CSR + inv_deg per segment, all bucket-local ----------
__global__ __launch_bounds__(256) void refine_kernel(
    const int* __restrict__ bins, const int* __restrict__ boff,
    int* __restrict__ adj,
    int* __restrict__ off_e, float* __restrict__ inv_e, int n_e,
    int* __restrict__ off_v, float* __restrict__ inv_v, int n_v,
    int nbE, int nb) {
    const int b = blockIdx.x;
    const bool isE = b < nbE;
    const int sLo = (isE ? b : b - nbE) << W_SHIFT;
    const int nseg = isE ? n_e : n_v;
    int* off = isE ? off_e : off_v;
    float* inv = isE ? inv_e : inv_v;

    __shared__ int cnt[W_BKT], cnt2[W_BKT], lofs[W_BKT];
    if (threadIdx.x < W_BKT) { cnt[threadIdx.x] = 0; cnt2[threadIdx.x] = 0; }
    __syncthreads();

    const int r0 = boff[b], r1 = boff[b + 1];
    for (int j = r0 + threadIdx.x; j < r1; j += 256)
        atomicAdd(&cnt[bins[j] >> 20], 1);
    __syncthreads();

    if (threadIdx.x < 64) {  // wave 0: scan the 64 counters
        int c = cnt[threadIdx.x];
        int x = c;
        #pragma unroll
        for (int d = 1; d < 64; d <<= 1) {
            int y = __shfl_up(x, d, 64);
            if ((threadIdx.x & 63) >= d) x += y;
        }
        int excl = x - c;
        lofs[threadIdx.x] = r0 + excl;
        int s = sLo + threadIdx.x;
        if (s < nseg) {
            off[s] = r0 + excl;
            inv[s] = c > 0 ? 1.0f / (float)c : 0.0f;
        }
    }
    __syncthreads();
    for (int j = r0 + threadIdx.x; j < r1; j += 256) {
        int rec = bins[j];
        int local = rec >> 20;
        int src = rec & 0xFFFFF;
        int r = atomicAdd(&cnt2[local], 1);
        adj[lofs[local] + r] = src;
    }
    if (threadIdx.x == 0) {
        if (b == nbE - 1) off_e[n_e] = boff[nbE];
        if (b == nb - 1)  off_v[n_v] = boff[nb];
    }
}

// ---------- 6/7. gather v2: wave per segment, 2 rows per wave-load ----------
// Lane layout: half = lane>>5 (row parity), cl = lane&31 (channel quad).
// 32 lanes x float4 = 512 B = one full row. 8-row unroll -> 4 row-loads in flight.
__global__ __launch_bounds__(256, 8) void gather_kernel(
    const float* __restrict__ rows, const float* __restrict__ w,
    const int* __restrict__ off, const int* __restrict__ adj,
    float* __restrict__ out, int n_seg) {
    const int seg = blockIdx.x * 4 + (threadIdx.x >> 6);
    if (seg >= n_seg) return;
    const int lane = threadIdx.x & 63;
    const int half = lane >> 5;
    const int cl = lane & 31;
    int j = off[seg];
    const int end = off[seg + 1];

    float4 a0 = make_float4(0.f, 0.f, 0.f, 0.f), a1 = a0, a2 = a0, a3 = a0;

    for (; j + 7 < end; j += 8) {
        int s0 = adj[j     + half];
        int s1 = adj[j + 2 + half];
        int s2 = adj[j + 4 + half];
        int s3 = adj[j + 6 + half];
        float w0 = w[s0], w1 = w[s1], w2 = w[s2], w3 = w[s3];
        float4 x0 = *reinterpret_cast<const float4*>(rows + (size_t)s0 * C_DIM + cl * 4);
        float4 x1 = *reinterpret_cast<const float4*>(rows + (size_t)s1 * C_DIM + cl * 4);
        float4 x2 = *reinterpret_cast<const float4*>(rows + (size_t)s2 * C_DIM + cl * 4);
        float4 x3 = *reinterpret_cast<const float4*>(rows + (size_t)s3 * C_DIM + cl * 4);
        a0.x += x0.x * w0; a0.y += x0.y * w0; a0.z += x0.z * w0; a0.w += x0.w * w0;
        a1.x += x1.x * w1; a1.y += x1.y * w1; a1.z += x1.z * w1; a1.w += x1.w * w1;
        a2.x += x2.x * w2; a2.y += x2.y * w2; a2.z += x2.z * w2; a2.w += x2.w * w2;
        a3.x += x3.x * w3; a3.y += x3.y * w3; a3.z += x3.z * w3; a3.w += x3.w * w3;
    }
    for (; j + 1 < end; j += 2) {
        int s0 = adj[j + half];
        float w0 = w[s0];
        float4 x0 = *reinterpret_cast<const float4*>(rows + (size_t)s0 * C_DIM + cl * 4);
        a0.x += x0.x * w0; a0.y += x0.y * w0; a0.z += x0.z * w0; a0.w += x0.w * w0;
    }
    if (j < end && half == 0) {  // odd tail: low half only
        int s0 = adj[j];
        float w0 = w[s0];
        float4 x0 = *reinterpret_cast<const float4*>(rows + (size_t)s0 * C_DIM + cl * 4);
        a0.x += x0.x * w0; a0.y += x0.y * w0; a0.z += x0.z * w0; a0.w += x0.w * w0;
    }

    float4 a;
    a.x = (a0.x + a1.x) + (a2.x + a3.x);
    a.y = (a0.y + a1.y) + (a2.y + a3.y);
    a.z = (a0.z + a1.z) + (a2.z + a3.z);
    a.w = (a0.w + a1.w) + (a2.w + a3.w);
    // combine row-parity halves (partner lane = lane ^ 32)
    a.x += __shfl_xor(a.x, 32, 64);
    a.y += __shfl_xor(a.y, 32, 64);
    a.z += __shfl_xor(a.z, 32, 64);
    a.w += __shfl_xor(a.w, 32, 64);
    if (half == 0)
        *reinterpret_cast<float4*>(out + (size_t)seg * C_DIM + cl * 4) = a;
}

extern "C" void kernel_launch(void* const* d_in, const int* in_sizes, int n_in,
                              void* d_out, int out_size, void* d_ws, size_t ws_size,
                              hipStream_t stream) {
    const float* X   = (const float*)d_in[0];
    const int* v_ids = (const int*)d_in[1];
    const int* e_ids = (const int*)d_in[2];

    const int n_v = in_sizes[0] / C_DIM;
    const int nnz = in_sizes[1];
    const int n_e = out_size / C_DIM - n_v;
    const int nbE = (n_e + W_BKT - 1) / W_BKT;
    const int nbV = (n_v + W_BKT - 1) / W_BKT;
    const int nb  = nbE + nbV;
    const int itemsPerBlk = (((nnz + NBLK - 1) / NBLK) + 3) & ~3;

    float* node_feat = (float*)d_out;                       // [n_v, 128]
    float* edge_feat = (float*)d_out + (size_t)n_v * C_DIM; // [n_e, 128]

    // workspace (4B units)
    int* ws = (int*)d_ws;
    size_t cur = 0;
    int* counts = ws + cur; cur += (size_t)nb * NBLK;
    int* totals = ws + cur; cur += nb;
    int* boff   = ws + cur; cur += nb + 1;
    int* off_e  = ws + cur; cur += n_e + 1;
    int* off_v  = ws + cur; cur += n_v + 1;
    float* inv_e = (float*)(ws + cur); cur += n_e;
    float* inv_v = (float*)(ws + cur); cur += n_v;
    int* bins = ws + cur; cur += 2 * (size_t)nnz;
    int* adj  = ws + cur; cur += 2 * (size_t)nnz;

    const size_t smem1 = (size_t)nb * sizeof(int);
    const size_t smem2 = 2 * (size_t)nb * sizeof(int);

    count_kernel<<<NBLK, 256, smem1, stream>>>(v_ids, e_ids, counts, nnz, nbE, nb, itemsPerBlk);
    colscan_kernel<<<(nb + 3) / 4, 256, 0, stream>>>(counts, totals, nb);
    bscan_kernel<<<1, 1024, 0, stream>>>(totals, boff, nb);
    place_kernel<<<NBLK, 256, smem2, stream>>>(v_ids, e_ids, counts, boff, bins,
                                               nnz, nbE, nb, itemsPerBlk);
    refine_kernel<<<nb, 256, 0, stream>>>(bins, boff, adj,
                                          off_e, inv_e, n_e,
                                          off_v, inv_v, n_v, nbE, nb);
    // v2e: edge_feat[e] = sum_v X[v] * inv_deg_v[v]
    gather_kernel<<<(n_e + 3) / 4, 256, 0, stream>>>(X, inv_v, off_e, adj, edge_feat, n_e);
    // e2v: node_feat[v] = sum_e edge_feat[e] * inv_deg_e[e]
    gather_kernel<<<(n_v + 3) / 4, 256, 0, stream>>>(edge_feat, inv_e, off_v, adj, node_feat, n_v);
}